// Round 3
// baseline (3112.365 us; speedup 1.0000x reference)
//
#include <hip/hip_runtime.h>
#include <stdint.h>

// Exact fp32 reproduction of the numpy reference requires no FMA contraction
// and identical association order everywhere below.
#pragma clang fp contract(off)

#define B_    4
#define NV_   6890
#define NF_   27552     // 2*13776
#define IMG_  128
#define UV_   256
#define NPIX  (IMG_*IMG_)

#define TS_     8                 // tile edge in pixels
#define TPB_    (IMG_/TS_)        // 16 tiles per row/col
#define NTILE_  (TPB_*TPB_)       // 256 tiles per batch
#define NBIN_   (B_*NTILE_)       // 1024 bins
#define NCHUNK_ 4                 // list chunks per tile (parallelism/balance)
#define LIST_CAP (2*1024*1024)    // entries (8 MB); expected ~0.9M

// ---------------------------------------------------------------- projection
__global__ void __launch_bounds__(256) project_k(
    const float* __restrict__ cam, const float* __restrict__ verts,
    float* __restrict__ vp) {
  int idx = blockIdx.x * 256 + threadIdx.x;
  if (idx >= B_ * NV_) return;
  int b = idx / NV_;
  float c0 = cam[b * 3 + 0], c1 = cam[b * 3 + 1], c2 = cam[b * 3 + 2];
  float tz = 500.0f / (64.0f * c0);                  // FLENGTH/(p*cam0), p=64
  const float* src = verts + (size_t)idx * 3;
  float* dst = vp + (size_t)idx * 3;
  dst[0] = c0 * (src[0] + c1);
  dst[1] = c0 * (src[1] + c2);
  dst[2] = src[2] + tz;
}

// ------------------------------------------------------------------- binning
// Backface cull (area_c < -1e-3, bit-safe bound proven in R1) + bbox(+-1px)
// -> range of overlapped 8x8 tiles. +-1 px margin: accepted pixels can exceed
// the fp bbox by <~1e-3 px only (fp error of w-tests ~1e-5 NDC).
__device__ __forceinline__ bool face_tiles(
    const float* __restrict__ vp, const int* __restrict__ faces, int b, int f,
    int& tx0, int& tx1, int& ty0, int& ty1) {
  int ia = faces[f * 3 + 0], ib = faces[f * 3 + 1], ic = faces[f * 3 + 2];
  const float* vb = vp + (size_t)b * NV_ * 3;
  float x0 = vb[ia * 3 + 0], y0 = vb[ia * 3 + 1];
  float x1 = vb[ib * 3 + 0], y1 = vb[ib * 3 + 1];
  float x2 = vb[ic * 3 + 0], y2 = vb[ic * 3 + 1];
  float area_c = (x1 - x0) * (y2 - y0) - (y1 - y0) * (x2 - x0);
  if (area_c < -1e-3f) return false;
  float xmn = fminf(x0, fminf(x1, x2)), xmx = fmaxf(x0, fmaxf(x1, x2));
  float ymn = fminf(y0, fminf(y1, y2)), ymx = fmaxf(y0, fmaxf(y1, y2));
  int jlo = (int)floorf((xmn + 1.0f) * 64.0f - 0.5f) - 1;
  int jhi = (int)ceilf ((xmx + 1.0f) * 64.0f - 0.5f) + 1;
  int ilo = (int)floorf((1.0f - ymx) * 64.0f - 0.5f) - 1;
  int ihi = (int)ceilf ((1.0f - ymn) * 64.0f - 0.5f) + 1;
  if (jhi < 0 || ihi < 0 || jlo > IMG_ - 1 || ilo > IMG_ - 1) return false;
  jlo = max(jlo, 0); ilo = max(ilo, 0);
  jhi = min(jhi, IMG_ - 1); ihi = min(ihi, IMG_ - 1);
  tx0 = jlo >> 3; tx1 = jhi >> 3; ty0 = ilo >> 3; ty1 = ihi >> 3;
  return true;
}

__global__ void __launch_bounds__(256) bin_count_k(
    const float* __restrict__ vp, const int* __restrict__ faces,
    int* __restrict__ cnt) {
  int idx = blockIdx.x * 256 + threadIdx.x;
  if (idx >= B_ * NF_) return;
  int b = idx / NF_, f = idx - b * NF_;
  int tx0, tx1, ty0, ty1;
  if (!face_tiles(vp, faces, b, f, tx0, tx1, ty0, ty1)) return;
  for (int ty = ty0; ty <= ty1; ++ty)
    for (int tx = tx0; tx <= tx1; ++tx)
      atomicAdd(&cnt[(b * TPB_ + ty) * TPB_ + tx], 1);
}

// exclusive scan over the 1024 bin counts; cursors start at the offsets
__global__ void __launch_bounds__(1024) scan_k(
    const int* __restrict__ cnt, int* __restrict__ off, int* __restrict__ cur) {
  __shared__ int sm[NBIN_];
  int t = threadIdx.x;
  int v = cnt[t];
  sm[t] = v;
  __syncthreads();
  for (int d = 1; d < NBIN_; d <<= 1) {
    int u = (t >= d) ? sm[t - d] : 0;
    __syncthreads();
    sm[t] += u;
    __syncthreads();
  }
  int o = sm[t] - v;
  off[t] = o;
  cur[t] = o;
}

__global__ void __launch_bounds__(256) bin_fill_k(
    const float* __restrict__ vp, const int* __restrict__ faces,
    int* __restrict__ cur, int* __restrict__ list) {
  int idx = blockIdx.x * 256 + threadIdx.x;
  if (idx >= B_ * NF_) return;
  int b = idx / NF_, f = idx - b * NF_;
  int tx0, tx1, ty0, ty1;
  if (!face_tiles(vp, faces, b, f, tx0, tx1, ty0, ty1)) return;
  for (int ty = ty0; ty <= ty1; ++ty)
    for (int tx = tx0; tx <= tx1; ++tx) {
      int slot = atomicAdd(&cur[(b * TPB_ + ty) * TPB_ + tx], 1);
      if (slot < LIST_CAP) list[slot] = f;
    }
}

// ---------------------------------------------------------------- rasterizer
// One wave per (bin, chunk). Thread <-> pixel of the 8x8 tile; lexicographic
// (zp_bits, fid) min kept in a register; faces staged 64-at-a-time via LDS
// (field-major: stride-1 writes, broadcast reads -> conflict-free).
// Inside test `area>0 && !(w<0)` proven exactly equivalent to the reference's
// post-divide b>=0 checks (w is 0 or >=~1e-35 in magnitude; area<=~30, so
// w/area never rounds to -0/+0 across sign). Accepted pixels run the
// reference's exact divide chain -> bit-identical zp; (zp,fid)-min is
// order-independent -> merge via one atomicMin per pixel per chunk.
__global__ void __launch_bounds__(64) raster_k(
    const float* __restrict__ vp, const int* __restrict__ faces,
    const int* __restrict__ list, const int* __restrict__ cnt,
    const int* __restrict__ off, unsigned long long* __restrict__ zkey) {
  int bin = blockIdx.x;
  int b = bin / NTILE_;
  int t = bin - b * NTILE_;
  int ty = t / TPB_, tx = t - ty * TPB_;
  int lane = threadIdx.x;
  int pi = ty * TS_ + (lane >> 3);
  int pj = tx * TS_ + (lane & 7);
  // exact: (2j+1)/128-1 and 1-(2i+1)/128 are multiples of 2^-7 in [-1,1]
  float px = fmaf((float)pj, 0.015625f, -0.9921875f);
  float py = fmaf((float)pi, -0.015625f, 0.9921875f);

  int n = cnt[bin];
  int base = off[bin];
  int nst = (n + 63) >> 6;

  __shared__ float fd[16][64];
  unsigned long long kb = ~0ull;

  for (int s = (int)blockIdx.y; s < nst; s += NCHUNK_) {
    int k = s * 64 + lane;
    if (k < n) {
      int fid = list[base + k];
      int ia = faces[fid * 3 + 0], ib = faces[fid * 3 + 1],
          ic = faces[fid * 3 + 2];
      const float* vb = vp + (size_t)b * NV_ * 3;
      float X0 = vb[ia * 3 + 0], Y0 = vb[ia * 3 + 1], Z0 = vb[ia * 3 + 2];
      float X1 = vb[ib * 3 + 0], Y1 = vb[ib * 3 + 1], Z1 = vb[ib * 3 + 2];
      float X2 = vb[ic * 3 + 0], Y2 = vb[ic * 3 + 1], Z2 = vb[ic * 3 + 2];
      fd[0][lane] = X0;  fd[1][lane] = Y0;
      fd[2][lane] = X1;  fd[3][lane] = Y1;
      fd[4][lane] = X2;  fd[5][lane] = Y2;
      fd[6][lane] = X2 - X1;  fd[7][lane] = Y2 - Y1;   // d21
      fd[8][lane] = X0 - X2;  fd[9][lane] = Y0 - Y2;   // d02
      fd[10][lane] = X1 - X0; fd[11][lane] = Y1 - Y0;  // d10
      fd[12][lane] = Z0; fd[13][lane] = Z1; fd[14][lane] = Z2;
      fd[15][lane] = __int_as_float(fid);
    }
    __syncthreads();
    int m = min(64, n - s * 64);
    for (int q = 0; q < m; ++q) {
      float y1 = fd[3][q], x1 = fd[2][q];
      float y2 = fd[5][q], x2 = fd[4][q];
      float y0 = fd[1][q], x0 = fd[0][q];
      float w0 = fd[6][q] * (py - y1) - fd[7][q] * (px - x1);
      float w1 = fd[8][q] * (py - y2) - fd[9][q] * (px - x2);
      float w2 = fd[10][q] * (py - y0) - fd[11][q] * (px - x0);
      float area = (w0 + w1) + w2;
      if (area > 0.0f && !(w0 < 0.0f) && !(w1 < 0.0f) && !(w2 < 0.0f)) {
        float z0 = fd[12][q], z1 = fd[13][q], z2 = fd[14][q];
        unsigned int fid = (unsigned int)__float_as_int(fd[15][q]);
        float b0 = w0 / area, b1 = w1 / area, b2 = w2 / area;
        float invz = (b0 / z0 + b1 / z1) + b2 / z2;
        float zp = 1.0f / (invz == 0.0f ? 1.0f : invz);
        if (zp > 0.1f && zp < 25.0f) {
          unsigned long long key =
              ((unsigned long long)__float_as_uint(zp) << 32) | fid;
          kb = key < kb ? key : kb;
        }
      }
    }
    __syncthreads();
  }
  if (kb != ~0ull)
    atomicMin(zkey + (size_t)b * NPIX + pi * IMG_ + pj, kb);
}

// ------------------------------------------------------------------- shading
#define TAP(ty, tx, wexpr)                                                   \
  {                                                                          \
    int ty_ = (ty), tx_ = (tx);                                              \
    float w_ = (wexpr);                                                      \
    float valid_ =                                                           \
        (tx_ >= 0 && tx_ < UV_ && ty_ >= 0 && ty_ < UV_) ? 1.0f : 0.0f;      \
    float wv_ = w_ * valid_;                                                 \
    int cy_ = min(max(ty_, 0), UV_ - 1), cx_ = min(max(tx_, 0), UV_ - 1);    \
    int o_ = cy_ * UV_ + cx_;                                                \
    cr = cr + img[o_] * wv_;                                                 \
    cg = cg + img[UV_ * UV_ + o_] * wv_;                                     \
    cb = cb + img[2 * UV_ * UV_ + o_] * wv_;                                 \
  }

__global__ void __launch_bounds__(256) shade_k(
    const float* __restrict__ vp, const int* __restrict__ faces,
    const float* __restrict__ uv, const float* __restrict__ samp,
    const unsigned long long* __restrict__ zkey, float* __restrict__ out) {
  int idx = blockIdx.x * 256 + threadIdx.x;
  if (idx >= B_ * NPIX) return;
  int b = idx / NPIX;
  int p = idx - b * NPIX;
  int ii = p / IMG_;
  int jj = p - ii * IMG_;

  unsigned long long key = zkey[idx];
  float cr = 0.0f, cg = 0.0f, cb = 0.0f;
  if (key != 0xFFFFFFFFFFFFFFFFull) {
    int f = (int)(key & 0xFFFFFFFFull);
    int ia = faces[f * 3 + 0], ib = faces[f * 3 + 1], ic = faces[f * 3 + 2];
    const float* vb = vp + (size_t)b * NV_ * 3;
    float x0 = vb[ia * 3 + 0], y0 = vb[ia * 3 + 1];
    float x1 = vb[ib * 3 + 0], y1 = vb[ib * 3 + 1];
    float x2 = vb[ic * 3 + 0], y2 = vb[ic * 3 + 1];
    float px = (float)(2 * jj + 1) / 128.0f - 1.0f;
    float py = 1.0f - (float)(2 * ii + 1) / 128.0f;
    float w0 = (x2 - x1) * (py - y1) - (y2 - y1) * (px - x1);
    float w1 = (x0 - x2) * (py - y2) - (y0 - y2) * (px - x2);
    float w2 = (x1 - x0) * (py - y0) - (y1 - y0) * (px - x0);
    float area = (w0 + w1) + w2;
    float s = (area == 0.0f) ? 1.0f : area;
    float b0 = w0 / s, b1 = w1 / s;
    int t0 = min(max((int)floorf(b0 * 3.0f), 0), 2);
    int t1 = min(max((int)floorf(b1 * 3.0f), 0), 2);

    // lazy texture fetch: textures[b,f,t0,t1,*,c] == bilinear(uv_imgs[b],
    // sampler[f, t0*3+t1]); lighting multiplier is exactly 1.0 -> skipped.
    const float* g = samp + ((size_t)f * 9 + (size_t)(t0 * 3 + t1)) * 2;
    float gx = g[0], gy = g[1];
    float x = (gx + 1.0f) * 128.0f - 0.5f;   // (g+1)*(W*0.5)-0.5, W=256
    float y = (gy + 1.0f) * 128.0f - 0.5f;
    float x0f = floorf(x), y0f = floorf(y);
    float wx = x - x0f, wy = y - y0f;
    int xi = (int)x0f, yi = (int)y0f;
    float omwx = 1.0f - wx, omwy = 1.0f - wy;
    const float* img = uv + (size_t)b * 3 * UV_ * UV_;
    // reference accumulation order: (y0,x0)+(y0,x0+1)+(y0+1,x0)+(y0+1,x0+1)
    TAP(yi,     xi,     omwx * omwy)
    TAP(yi,     xi + 1, wx * omwy)
    TAP(yi + 1, xi,     omwx * wy)
    TAP(yi + 1, xi + 1, wx * wy)
  }
  out[((size_t)b * 3 + 0) * NPIX + p] = cr;
  out[((size_t)b * 3 + 1) * NPIX + p] = cg;
  out[((size_t)b * 3 + 2) * NPIX + p] = cb;
}

// ------------------------------------------------------------------- launch
extern "C" void kernel_launch(void* const* d_in, const int* in_sizes, int n_in,
                              void* d_out, int out_size, void* d_ws,
                              size_t ws_size, hipStream_t stream) {
  const float* cam   = (const float*)d_in[0];
  const float* verts = (const float*)d_in[1];
  const float* uv    = (const float*)d_in[2];
  const float* samp  = (const float*)d_in[3];
  const int*   faces = (const int*)d_in[4];

  char* ws = (char*)d_ws;
  size_t o = 0;
  unsigned long long* zkey = (unsigned long long*)(ws + o); o += (size_t)B_ * NPIX * 8;      // 512 KB
  float* vp  = (float*)(ws + o); o += ((size_t)B_ * NV_ * 3 * 4 + 1023) & ~1023ull;          // ~331 KB
  int* cnt   = (int*)(ws + o); o += NBIN_ * 4;
  int* offs  = (int*)(ws + o); o += NBIN_ * 4;
  int* cur   = (int*)(ws + o); o += NBIN_ * 4;
  int* list  = (int*)(ws + o);                                                               // 8 MB

  hipMemsetAsync(zkey, 0xFF, (size_t)B_ * NPIX * 8, stream);
  hipMemsetAsync(cnt, 0, NBIN_ * 4, stream);
  project_k<<<(B_ * NV_ + 255) / 256, 256, 0, stream>>>(cam, verts, vp);
  bin_count_k<<<(B_ * NF_ + 255) / 256, 256, 0, stream>>>(vp, faces, cnt);
  scan_k<<<1, NBIN_, 0, stream>>>(cnt, offs, cur);
  bin_fill_k<<<(B_ * NF_ + 255) / 256, 256, 0, stream>>>(vp, faces, cur, list);
  raster_k<<<dim3(NBIN_, NCHUNK_), 64, 0, stream>>>(vp, faces, list, cnt, offs,
                                                    zkey);
  shade_k<<<(B_ * NPIX + 255) / 256, 256, 0, stream>>>(vp, faces, uv, samp,
                                                       zkey, (float*)d_out);
}

// Round 4
// 595.304 us; speedup vs baseline: 5.2282x; 5.2282x over previous
//
#include <hip/hip_runtime.h>
#include <stdint.h>

// Exact fp32 reproduction of the numpy reference requires no FMA contraction
// and identical association order everywhere below.
#pragma clang fp contract(off)

#define B_    4
#define NV_   6890
#define NF_   27552     // 2*13776
#define IMG_  128
#define UV_   256
#define NPIX  (IMG_*IMG_)

#define TS_     8                 // tile edge in pixels
#define TPB_    (IMG_/TS_)        // 16 tiles per row/col
#define NTILE_  (TPB_*TPB_)       // 256 tiles per batch
#define NBIN_   (B_*NTILE_)       // 1024 bins
#define LIST_CAP (2*1024*1024)    // entries (8 MB); expected ~1.2M
#define MAXC_   (LIST_CAP/256 + NBIN_)  // 9216: hard bound on work chunks

// ---------------------------------------------------------------- projection
__global__ void __launch_bounds__(256) project_k(
    const float* __restrict__ cam, const float* __restrict__ verts,
    float* __restrict__ vp) {
  int idx = blockIdx.x * 256 + threadIdx.x;
  if (idx >= B_ * NV_) return;
  int b = idx / NV_;
  float c0 = cam[b * 3 + 0], c1 = cam[b * 3 + 1], c2 = cam[b * 3 + 2];
  float tz = 500.0f / (64.0f * c0);                  // FLENGTH/(p*cam0), p=64
  const float* src = verts + (size_t)idx * 3;
  float* dst = vp + (size_t)idx * 3;
  dst[0] = c0 * (src[0] + c1);
  dst[1] = c0 * (src[1] + c2);
  dst[2] = src[2] + tz;
}

// ------------------------------------------------------------------- binning
// Backface cull (area_c < -1e-3, bit-safe bound proven in R1) + bbox(+-1px)
// -> range of overlapped 8x8 tiles. +-1 px margin: accepted pixels can exceed
// the fp bbox by <~1e-3 px only (fp error of w-tests ~1e-5 NDC).
__device__ __forceinline__ int face_tiles(
    const float* __restrict__ vp, const int* __restrict__ faces, int b, int f,
    int& tx0, int& tx1, int& ty0, int& ty1) {
  int ia = faces[f * 3 + 0], ib = faces[f * 3 + 1], ic = faces[f * 3 + 2];
  const float* vb = vp + (size_t)b * NV_ * 3;
  float x0 = vb[ia * 3 + 0], y0 = vb[ia * 3 + 1];
  float x1 = vb[ib * 3 + 0], y1 = vb[ib * 3 + 1];
  float x2 = vb[ic * 3 + 0], y2 = vb[ic * 3 + 1];
  float area_c = (x1 - x0) * (y2 - y0) - (y1 - y0) * (x2 - x0);
  if (area_c < -1e-3f) return 0;
  float xmn = fminf(x0, fminf(x1, x2)), xmx = fmaxf(x0, fmaxf(x1, x2));
  float ymn = fminf(y0, fminf(y1, y2)), ymx = fmaxf(y0, fmaxf(y1, y2));
  int jlo = (int)floorf((xmn + 1.0f) * 64.0f - 0.5f) - 1;
  int jhi = (int)ceilf ((xmx + 1.0f) * 64.0f - 0.5f) + 1;
  int ilo = (int)floorf((1.0f - ymx) * 64.0f - 0.5f) - 1;
  int ihi = (int)ceilf ((1.0f - ymn) * 64.0f - 0.5f) + 1;
  if (jhi < 0 || ihi < 0 || jlo > IMG_ - 1 || ilo > IMG_ - 1) return 0;
  jlo = max(jlo, 0); ilo = max(ilo, 0);
  jhi = min(jhi, IMG_ - 1); ihi = min(ihi, IMG_ - 1);
  tx0 = jlo >> 3; tx1 = jhi >> 3; ty0 = ilo >> 3; ty1 = ihi >> 3;
  return 1;
}

// Wave-aggregated count: loop tiles wave-uniformly; ONE atomic per wave per
// covered bin (hot central counters see <=430 atomics instead of ~40K).
__global__ void __launch_bounds__(256) bin_count_k(
    const float* __restrict__ vp, const int* __restrict__ faces,
    int* __restrict__ cnt) {
  int f = blockIdx.x * 256 + threadIdx.x;
  int b = blockIdx.y;
  int lane = threadIdx.x & 63;
  int tx0 = 16, tx1 = -1, ty0 = 16, ty1 = -1;
  int valid = 0;
  if (f < NF_) valid = face_tiles(vp, faces, b, f, tx0, tx1, ty0, ty1);
  for (int ty = 0; ty < TPB_; ++ty)
    for (int tx = 0; tx < TPB_; ++tx) {
      bool cov = valid && tx >= tx0 && tx <= tx1 && ty >= ty0 && ty <= ty1;
      unsigned long long m = __ballot(cov);
      if (m) {
        int leader = __ffsll((long long)m) - 1;
        if (lane == leader)
          atomicAdd(&cnt[(b * TPB_ + ty) * TPB_ + tx], __popcll(m));
      }
    }
}

// Scan bin counts -> offsets; also scan chunk counts (ceil(cnt/256)) into a
// flat balanced work list of (bin, chunk) pairs; total chunk count -> nC.
__global__ void __launch_bounds__(1024) scan_k(
    const int* __restrict__ cnt, int* __restrict__ off, int* __restrict__ cur,
    int* __restrict__ work, int* __restrict__ nC) {
  __shared__ int sm[NBIN_];
  int t = threadIdx.x;
  int v = cnt[t];
  sm[t] = v;
  __syncthreads();
  for (int d = 1; d < NBIN_; d <<= 1) {
    int u = (t >= d) ? sm[t - d] : 0;
    __syncthreads();
    sm[t] += u;
    __syncthreads();
  }
  int o = sm[t] - v;
  off[t] = o;
  cur[t] = o;
  int nch = (v + 255) >> 8;
  __syncthreads();
  sm[t] = nch;
  __syncthreads();
  for (int d = 1; d < NBIN_; d <<= 1) {
    int u = (t >= d) ? sm[t - d] : 0;
    __syncthreads();
    sm[t] += u;
    __syncthreads();
  }
  int cb = sm[t] - nch;
  if (t == NBIN_ - 1) nC[0] = sm[t];
  for (int c = 0; c < nch; ++c) work[cb + c] = t | (c << 10);
}

// Wave-aggregated fill: one reservation atomic per wave per bin; lanes place
// their entries at base+rank (rank = popcount of earlier covered lanes).
// List order is irrelevant: the (zp,fid) lexicographic min is order-free.
__global__ void __launch_bounds__(256) bin_fill_k(
    const float* __restrict__ vp, const int* __restrict__ faces,
    int* __restrict__ cur, int* __restrict__ list) {
  int f = blockIdx.x * 256 + threadIdx.x;
  int b = blockIdx.y;
  int lane = threadIdx.x & 63;
  int tx0 = 16, tx1 = -1, ty0 = 16, ty1 = -1;
  int valid = 0;
  if (f < NF_) valid = face_tiles(vp, faces, b, f, tx0, tx1, ty0, ty1);
  for (int ty = 0; ty < TPB_; ++ty)
    for (int tx = 0; tx < TPB_; ++tx) {
      bool cov = valid && tx >= tx0 && tx <= tx1 && ty >= ty0 && ty <= ty1;
      unsigned long long m = __ballot(cov);
      if (m) {
        int leader = __ffsll((long long)m) - 1;
        int basev = 0;
        if (lane == leader)
          basev = atomicAdd(&cur[(b * TPB_ + ty) * TPB_ + tx], __popcll(m));
        basev = __shfl(basev, leader, 64);
        if (cov) {
          int rank = __popcll(m & ((1ull << lane) - 1ull));
          int slot = basev + rank;
          if (slot < LIST_CAP) list[slot] = f;
        }
      }
    }
}

// ---------------------------------------------------------------- rasterizer
// One 256-thread block per work chunk (bin, 256 faces) -> perfectly uniform
// load. Wave w stages its 64 faces into LDS as float4s (ds_write_b128);
// inner loop reads 3-4 uniform-address ds_read_b128 broadcasts per face.
// Inside test `area>0 && !(w<0)` proven exactly equivalent to the reference's
// post-divide b>=0 checks (R3 validated, absmax 0.0). Accepted pixels run the
// reference's exact divide chain -> bit-identical zp; block merges 4 waves'
// per-pixel mins in LDS -> ONE atomicMin per pixel per block.
__global__ void __launch_bounds__(256) raster_k(
    const float* __restrict__ vp, const int* __restrict__ faces,
    const int* __restrict__ list, const int* __restrict__ cnt,
    const int* __restrict__ off, const int* __restrict__ work,
    const int* __restrict__ nC, unsigned long long* __restrict__ zkey) {
  __shared__ float4 fd[4][64][4];
  __shared__ unsigned long long mg[4][64];
  int bid = blockIdx.x;
  if (bid >= nC[0]) return;                       // block-uniform exit
  int wkv = work[bid];
  int bin = wkv & (NBIN_ - 1);
  int chunk = wkv >> 10;
  int b = bin >> 8;
  int t = bin & 255;
  int tyT = t >> 4, txT = t & 15;
  int ws = threadIdx.x >> 6, lane = threadIdx.x & 63;
  int pi = tyT * TS_ + (lane >> 3);
  int pj = txT * TS_ + (lane & 7);
  // exact: (2j+1)/128-1 and 1-(2i+1)/128 are multiples of 2^-7 in [-1,1]
  float px = fmaf((float)pj, 0.015625f, -0.9921875f);
  float py = fmaf((float)pi, -0.015625f, 0.9921875f);

  int n = cnt[bin];
  int seg = (chunk << 8) + (ws << 6);
  int base0 = off[bin] + seg;
  int mw = min(n - seg, 64);
  mw = max(mw, 0);

  if (lane < mw) {
    int fid = list[base0 + lane];
    int ia = faces[fid * 3 + 0], ib = faces[fid * 3 + 1],
        ic = faces[fid * 3 + 2];
    const float* vb = vp + (size_t)b * NV_ * 3;
    float X0 = vb[ia * 3 + 0], Y0 = vb[ia * 3 + 1], Z0 = vb[ia * 3 + 2];
    float X1 = vb[ib * 3 + 0], Y1 = vb[ib * 3 + 1], Z1 = vb[ib * 3 + 2];
    float X2 = vb[ic * 3 + 0], Y2 = vb[ic * 3 + 1], Z2 = vb[ic * 3 + 2];
    fd[ws][lane][0] = make_float4(X2 - X1, Y2 - Y1, X1, Y1);   // d21, v1
    fd[ws][lane][1] = make_float4(X0 - X2, Y0 - Y2, X2, Y2);   // d02, v2
    fd[ws][lane][2] = make_float4(X1 - X0, Y1 - Y0, X0, Y0);   // d10, v0
    fd[ws][lane][3] = make_float4(Z0, Z1, Z2, __int_as_float(fid));
  }
  __syncthreads();

  unsigned long long kb = ~0ull;
  for (int q = 0; q < mw; ++q) {
    float4 A = fd[ws][q][0];
    float4 Bv = fd[ws][q][1];
    float4 Cv = fd[ws][q][2];
    float w0 = A.x * (py - A.w) - A.y * (px - A.z);
    float w1 = Bv.x * (py - Bv.w) - Bv.y * (px - Bv.z);
    float w2 = Cv.x * (py - Cv.w) - Cv.y * (px - Cv.z);
    float area = (w0 + w1) + w2;
    if (area > 0.0f && !(w0 < 0.0f) && !(w1 < 0.0f) && !(w2 < 0.0f)) {
      float4 Z = fd[ws][q][3];
      float b0 = w0 / area, b1 = w1 / area, b2 = w2 / area;
      float invz = (b0 / Z.x + b1 / Z.y) + b2 / Z.z;
      float zp = 1.0f / (invz == 0.0f ? 1.0f : invz);
      if (zp > 0.1f && zp < 25.0f) {
        unsigned long long key =
            ((unsigned long long)__float_as_uint(zp) << 32) |
            (unsigned int)__float_as_int(Z.w);
        kb = key < kb ? key : kb;
      }
    }
  }

  mg[ws][lane] = kb;
  __syncthreads();
  if (ws == 0) {
    unsigned long long k0 = mg[0][lane];
    unsigned long long k1 = mg[1][lane];
    unsigned long long k2 = mg[2][lane];
    unsigned long long k3 = mg[3][lane];
    k0 = k1 < k0 ? k1 : k0;
    k2 = k3 < k2 ? k3 : k2;
    k0 = k2 < k0 ? k2 : k0;
    if (k0 != ~0ull)
      atomicMin(zkey + (size_t)b * NPIX + pi * IMG_ + pj, k0);
  }
}

// ------------------------------------------------------------------- shading
#define TAP(ty, tx, wexpr)                                                   \
  {                                                                          \
    int ty_ = (ty), tx_ = (tx);                                              \
    float w_ = (wexpr);                                                      \
    float valid_ =                                                           \
        (tx_ >= 0 && tx_ < UV_ && ty_ >= 0 && ty_ < UV_) ? 1.0f : 0.0f;      \
    float wv_ = w_ * valid_;                                                 \
    int cy_ = min(max(ty_, 0), UV_ - 1), cx_ = min(max(tx_, 0), UV_ - 1);    \
    int o_ = cy_ * UV_ + cx_;                                                \
    cr = cr + img[o_] * wv_;                                                 \
    cg = cg + img[UV_ * UV_ + o_] * wv_;                                     \
    cb = cb + img[2 * UV_ * UV_ + o_] * wv_;                                 \
  }

__global__ void __launch_bounds__(256) shade_k(
    const float* __restrict__ vp, const int* __restrict__ faces,
    const float* __restrict__ uv, const float* __restrict__ samp,
    const unsigned long long* __restrict__ zkey, float* __restrict__ out) {
  int idx = blockIdx.x * 256 + threadIdx.x;
  if (idx >= B_ * NPIX) return;
  int b = idx / NPIX;
  int p = idx - b * NPIX;
  int ii = p / IMG_;
  int jj = p - ii * IMG_;

  unsigned long long key = zkey[idx];
  float cr = 0.0f, cg = 0.0f, cb = 0.0f;
  if (key != 0xFFFFFFFFFFFFFFFFull) {
    int f = (int)(key & 0xFFFFFFFFull);
    int ia = faces[f * 3 + 0], ib = faces[f * 3 + 1], ic = faces[f * 3 + 2];
    const float* vb = vp + (size_t)b * NV_ * 3;
    float x0 = vb[ia * 3 + 0], y0 = vb[ia * 3 + 1];
    float x1 = vb[ib * 3 + 0], y1 = vb[ib * 3 + 1];
    float x2 = vb[ic * 3 + 0], y2 = vb[ic * 3 + 1];
    float px = (float)(2 * jj + 1) / 128.0f - 1.0f;
    float py = 1.0f - (float)(2 * ii + 1) / 128.0f;
    float w0 = (x2 - x1) * (py - y1) - (y2 - y1) * (px - x1);
    float w1 = (x0 - x2) * (py - y2) - (y0 - y2) * (px - x2);
    float w2 = (x1 - x0) * (py - y0) - (y1 - y0) * (px - x0);
    float area = (w0 + w1) + w2;
    float s = (area == 0.0f) ? 1.0f : area;
    float b0 = w0 / s, b1 = w1 / s;
    int t0 = min(max((int)floorf(b0 * 3.0f), 0), 2);
    int t1 = min(max((int)floorf(b1 * 3.0f), 0), 2);

    // lazy texture fetch: textures[b,f,t0,t1,*,c] == bilinear(uv_imgs[b],
    // sampler[f, t0*3+t1]); lighting multiplier is exactly 1.0 -> skipped.
    const float* g = samp + ((size_t)f * 9 + (size_t)(t0 * 3 + t1)) * 2;
    float gx = g[0], gy = g[1];
    float x = (gx + 1.0f) * 128.0f - 0.5f;   // (g+1)*(W*0.5)-0.5, W=256
    float y = (gy + 1.0f) * 128.0f - 0.5f;
    float x0f = floorf(x), y0f = floorf(y);
    float wx = x - x0f, wy = y - y0f;
    int xi = (int)x0f, yi = (int)y0f;
    float omwx = 1.0f - wx, omwy = 1.0f - wy;
    const float* img = uv + (size_t)b * 3 * UV_ * UV_;
    // reference accumulation order: (y0,x0)+(y0,x0+1)+(y0+1,x0)+(y0+1,x0+1)
    TAP(yi,     xi,     omwx * omwy)
    TAP(yi,     xi + 1, wx * omwy)
    TAP(yi + 1, xi,     omwx * wy)
    TAP(yi + 1, xi + 1, wx * wy)
  }
  out[((size_t)b * 3 + 0) * NPIX + p] = cr;
  out[((size_t)b * 3 + 1) * NPIX + p] = cg;
  out[((size_t)b * 3 + 2) * NPIX + p] = cb;
}

// ------------------------------------------------------------------- launch
extern "C" void kernel_launch(void* const* d_in, const int* in_sizes, int n_in,
                              void* d_out, int out_size, void* d_ws,
                              size_t ws_size, hipStream_t stream) {
  const float* cam   = (const float*)d_in[0];
  const float* verts = (const float*)d_in[1];
  const float* uv    = (const float*)d_in[2];
  const float* samp  = (const float*)d_in[3];
  const int*   faces = (const int*)d_in[4];

  char* ws = (char*)d_ws;
  size_t o = 0;
  unsigned long long* zkey = (unsigned long long*)(ws + o);
  o += (size_t)B_ * NPIX * 8;                                   // 512 KB
  float* vp = (float*)(ws + o);
  o += ((size_t)B_ * NV_ * 3 * 4 + 1023) & ~1023ull;            // ~331 KB
  int* cnt  = (int*)(ws + o); o += NBIN_ * 4;
  int* offs = (int*)(ws + o); o += NBIN_ * 4;
  int* cur  = (int*)(ws + o); o += NBIN_ * 4;
  int* nC   = (int*)(ws + o); o += 1024;
  int* work = (int*)(ws + o); o += (size_t)MAXC_ * 4;           // 36 KB
  int* list = (int*)(ws + o);                                   // 8 MB

  hipMemsetAsync(zkey, 0xFF, (size_t)B_ * NPIX * 8, stream);
  hipMemsetAsync(cnt, 0, NBIN_ * 4, stream);
  project_k<<<(B_ * NV_ + 255) / 256, 256, 0, stream>>>(cam, verts, vp);
  dim3 bgrid((NF_ + 255) / 256, B_);
  bin_count_k<<<bgrid, 256, 0, stream>>>(vp, faces, cnt);
  scan_k<<<1, NBIN_, 0, stream>>>(cnt, offs, cur, work, nC);
  bin_fill_k<<<bgrid, 256, 0, stream>>>(vp, faces, cur, list);
  raster_k<<<MAXC_, 256, 0, stream>>>(vp, faces, list, cnt, offs, work, nC,
                                      zkey);
  shade_k<<<(B_ * NPIX + 255) / 256, 256, 0, stream>>>(vp, faces, uv, samp,
                                                       zkey, (float*)d_out);
}

// Round 5
// 248.476 us; speedup vs baseline: 12.5258x; 2.3958x over previous
//
#include <hip/hip_runtime.h>
#include <stdint.h>

// Exact fp32 reproduction of the numpy reference requires no FMA contraction
// and identical association order everywhere below.
#pragma clang fp contract(off)

#define B_    4
#define NV_   6890
#define NF_   27552     // 2*13776
#define IMG_  128
#define UV_   256
#define NPIX  (IMG_*IMG_)

#define TS_     8                 // tile edge in pixels
#define TPB_    (IMG_/TS_)        // 16 tiles per row/col
#define NTILE_  (TPB_*TPB_)       // 256 tiles per batch
#define NBIN_   (B_*NTILE_)       // 1024 bins
#define LIST_CAP (2*1024*1024)    // entries (8 MB); measured need ~1.2M
#define MAXC_   (LIST_CAP/256 + NBIN_)  // 9216: hard bound on work chunks

// ---------------------------------------------------------------- projection
__global__ void __launch_bounds__(256) project_k(
    const float* __restrict__ cam, const float* __restrict__ verts,
    float* __restrict__ vp) {
  int idx = blockIdx.x * 256 + threadIdx.x;
  if (idx >= B_ * NV_) return;
  int b = idx / NV_;
  float c0 = cam[b * 3 + 0], c1 = cam[b * 3 + 1], c2 = cam[b * 3 + 2];
  float tz = 500.0f / (64.0f * c0);                  // FLENGTH/(p*cam0), p=64
  const float* src = verts + (size_t)idx * 3;
  float* dst = vp + (size_t)idx * 3;
  dst[0] = c0 * (src[0] + c1);
  dst[1] = c0 * (src[1] + c2);
  dst[2] = src[2] + tz;
}

// ------------------------------------------------------------------- binning
// Backface cull (area_c < -1e-3, bit-safe bound proven in R1) + bbox(+-1px)
// -> range of overlapped 8x8 tiles. +-1 px margin: accepted pixels can exceed
// the fp bbox by <~1e-3 px only (fp error of w-tests ~1e-5 NDC).
__device__ __forceinline__ int face_tiles(
    const float* __restrict__ vp, const int* __restrict__ faces, int b, int f,
    int& tx0, int& tx1, int& ty0, int& ty1) {
  int ia = faces[f * 3 + 0], ib = faces[f * 3 + 1], ic = faces[f * 3 + 2];
  const float* vb = vp + (size_t)b * NV_ * 3;
  float x0 = vb[ia * 3 + 0], y0 = vb[ia * 3 + 1];
  float x1 = vb[ib * 3 + 0], y1 = vb[ib * 3 + 1];
  float x2 = vb[ic * 3 + 0], y2 = vb[ic * 3 + 1];
  float area_c = (x1 - x0) * (y2 - y0) - (y1 - y0) * (x2 - x0);
  if (area_c < -1e-3f) return 0;
  float xmn = fminf(x0, fminf(x1, x2)), xmx = fmaxf(x0, fmaxf(x1, x2));
  float ymn = fminf(y0, fminf(y1, y2)), ymx = fmaxf(y0, fmaxf(y1, y2));
  int jlo = (int)floorf((xmn + 1.0f) * 64.0f - 0.5f) - 1;
  int jhi = (int)ceilf ((xmx + 1.0f) * 64.0f - 0.5f) + 1;
  int ilo = (int)floorf((1.0f - ymx) * 64.0f - 0.5f) - 1;
  int ihi = (int)ceilf ((1.0f - ymn) * 64.0f - 0.5f) + 1;
  if (jhi < 0 || ihi < 0 || jlo > IMG_ - 1 || ilo > IMG_ - 1) return 0;
  jlo = max(jlo, 0); ilo = max(ilo, 0);
  jhi = min(jhi, IMG_ - 1); ihi = min(ihi, IMG_ - 1);
  tx0 = jlo >> 3; tx1 = jhi >> 3; ty0 = ilo >> 3; ty1 = ihi >> 3;
  return 1;
}

// Block-local LDS count aggregation: threads walk ONLY their face's covered
// tile rectangle (~21 tiles avg) with LDS atomics; one global atomicAdd per
// (block, nonempty bin) at the end. Hot global counters see <=216 RMWs.
__global__ void __launch_bounds__(256) bin_count_k(
    const float* __restrict__ vp, const int* __restrict__ faces,
    int* __restrict__ cnt) {
  __shared__ int scnt[NTILE_];
  int f = blockIdx.x * 256 + threadIdx.x;
  int b = blockIdx.y;
  scnt[threadIdx.x] = 0;
  __syncthreads();
  int tx0, tx1, ty0, ty1;
  int valid = (f < NF_) ? face_tiles(vp, faces, b, f, tx0, tx1, ty0, ty1) : 0;
  if (valid)
    for (int ty = ty0; ty <= ty1; ++ty)
      for (int tx = tx0; tx <= tx1; ++tx)
        atomicAdd(&scnt[ty * TPB_ + tx], 1);
  __syncthreads();
  int t = threadIdx.x;
  int v = scnt[t];
  if (v > 0) atomicAdd(&cnt[b * NTILE_ + t], v);
}

// Scan bin counts -> offsets; also scan chunk counts (ceil(cnt/256)) into a
// flat balanced work list of (bin, chunk) pairs; total chunk count -> nC.
__global__ void __launch_bounds__(1024) scan_k(
    const int* __restrict__ cnt, int* __restrict__ off, int* __restrict__ cur,
    int* __restrict__ work, int* __restrict__ nC) {
  __shared__ int sm[NBIN_];
  int t = threadIdx.x;
  int v = cnt[t];
  sm[t] = v;
  __syncthreads();
  for (int d = 1; d < NBIN_; d <<= 1) {
    int u = (t >= d) ? sm[t - d] : 0;
    __syncthreads();
    sm[t] += u;
    __syncthreads();
  }
  int o = sm[t] - v;
  off[t] = o;
  cur[t] = o;
  int nch = (v + 255) >> 8;
  __syncthreads();
  sm[t] = nch;
  __syncthreads();
  for (int d = 1; d < NBIN_; d <<= 1) {
    int u = (t >= d) ? sm[t - d] : 0;
    __syncthreads();
    sm[t] += u;
    __syncthreads();
  }
  int cb = sm[t] - nch;
  if (t == NBIN_ - 1) nC[0] = sm[t];
  for (int c = 0; c < nch; ++c) work[cb + c] = t | (c << 10);
}

// Block-local fill: stage 1 counts (LDS), one global reservation atomic per
// (block, bin) -> block base; stage 2 re-walks the rectangle, LDS-atomic rank
// -> list[base+rank]. Segments are contiguous per (block,bin) -> coalesced
// bursts. List order is irrelevant: the (zp,fid) min is order-free.
__global__ void __launch_bounds__(256) bin_fill_k(
    const float* __restrict__ vp, const int* __restrict__ faces,
    int* __restrict__ cur, int* __restrict__ list) {
  __shared__ int scnt[NTILE_];
  __shared__ int sbase[NTILE_];
  int f = blockIdx.x * 256 + threadIdx.x;
  int b = blockIdx.y;
  scnt[threadIdx.x] = 0;
  __syncthreads();
  int tx0, tx1, ty0, ty1;
  int valid = (f < NF_) ? face_tiles(vp, faces, b, f, tx0, tx1, ty0, ty1) : 0;
  if (valid)
    for (int ty = ty0; ty <= ty1; ++ty)
      for (int tx = tx0; tx <= tx1; ++tx)
        atomicAdd(&scnt[ty * TPB_ + tx], 1);
  __syncthreads();
  int t = threadIdx.x;
  int v = scnt[t];
  if (v > 0) sbase[t] = atomicAdd(&cur[b * NTILE_ + t], v);
  __syncthreads();
  scnt[t] = 0;            // reuse as per-bin rank counter
  __syncthreads();
  if (valid)
    for (int ty = ty0; ty <= ty1; ++ty)
      for (int tx = tx0; tx <= tx1; ++tx) {
        int bin = ty * TPB_ + tx;
        int r = atomicAdd(&scnt[bin], 1);
        int slot = sbase[bin] + r;
        if (slot < LIST_CAP) list[slot] = f;
      }
}

// ---------------------------------------------------------------- rasterizer
// One 256-thread block per work chunk (bin, 256 faces) -> perfectly uniform
// load. Wave w stages its 64 faces into LDS as float4s (ds_write_b128);
// inner loop reads 3-4 uniform-address ds_read_b128 broadcasts per face.
// Inside test `area>0 && !(w<0)` proven exactly equivalent to the reference's
// post-divide b>=0 checks (R3/R4 validated, absmax 0.0). Accepted pixels run
// the reference's exact divide chain -> bit-identical zp; block merges 4
// waves' per-pixel mins in LDS -> ONE atomicMin per pixel per block.
__global__ void __launch_bounds__(256) raster_k(
    const float* __restrict__ vp, const int* __restrict__ faces,
    const int* __restrict__ list, const int* __restrict__ cnt,
    const int* __restrict__ off, const int* __restrict__ work,
    const int* __restrict__ nC, unsigned long long* __restrict__ zkey) {
  __shared__ float4 fd[4][64][4];
  __shared__ unsigned long long mg[4][64];
  int bid = blockIdx.x;
  if (bid >= nC[0]) return;                       // block-uniform exit
  int wkv = work[bid];
  int bin = wkv & (NBIN_ - 1);
  int chunk = wkv >> 10;
  int b = bin >> 8;
  int t = bin & 255;
  int tyT = t >> 4, txT = t & 15;
  int ws = threadIdx.x >> 6, lane = threadIdx.x & 63;
  int pi = tyT * TS_ + (lane >> 3);
  int pj = txT * TS_ + (lane & 7);
  // exact: (2j+1)/128-1 and 1-(2i+1)/128 are multiples of 2^-7 in [-1,1]
  float px = fmaf((float)pj, 0.015625f, -0.9921875f);
  float py = fmaf((float)pi, -0.015625f, 0.9921875f);

  int n = cnt[bin];
  int seg = (chunk << 8) + (ws << 6);
  int base0 = off[bin] + seg;
  int mw = min(n - seg, 64);
  mw = max(mw, 0);

  if (lane < mw) {
    int fid = list[base0 + lane];
    int ia = faces[fid * 3 + 0], ib = faces[fid * 3 + 1],
        ic = faces[fid * 3 + 2];
    const float* vb = vp + (size_t)b * NV_ * 3;
    float X0 = vb[ia * 3 + 0], Y0 = vb[ia * 3 + 1], Z0 = vb[ia * 3 + 2];
    float X1 = vb[ib * 3 + 0], Y1 = vb[ib * 3 + 1], Z1 = vb[ib * 3 + 2];
    float X2 = vb[ic * 3 + 0], Y2 = vb[ic * 3 + 1], Z2 = vb[ic * 3 + 2];
    fd[ws][lane][0] = make_float4(X2 - X1, Y2 - Y1, X1, Y1);   // d21, v1
    fd[ws][lane][1] = make_float4(X0 - X2, Y0 - Y2, X2, Y2);   // d02, v2
    fd[ws][lane][2] = make_float4(X1 - X0, Y1 - Y0, X0, Y0);   // d10, v0
    fd[ws][lane][3] = make_float4(Z0, Z1, Z2, __int_as_float(fid));
  }
  __syncthreads();

  unsigned long long kb = ~0ull;
  for (int q = 0; q < mw; ++q) {
    float4 A = fd[ws][q][0];
    float4 Bv = fd[ws][q][1];
    float4 Cv = fd[ws][q][2];
    float w0 = A.x * (py - A.w) - A.y * (px - A.z);
    float w1 = Bv.x * (py - Bv.w) - Bv.y * (px - Bv.z);
    float w2 = Cv.x * (py - Cv.w) - Cv.y * (px - Cv.z);
    float area = (w0 + w1) + w2;
    if (area > 0.0f && !(w0 < 0.0f) && !(w1 < 0.0f) && !(w2 < 0.0f)) {
      float4 Z = fd[ws][q][3];
      float b0 = w0 / area, b1 = w1 / area, b2 = w2 / area;
      float invz = (b0 / Z.x + b1 / Z.y) + b2 / Z.z;
      float zp = 1.0f / (invz == 0.0f ? 1.0f : invz);
      if (zp > 0.1f && zp < 25.0f) {
        unsigned long long key =
            ((unsigned long long)__float_as_uint(zp) << 32) |
            (unsigned int)__float_as_int(Z.w);
        kb = key < kb ? key : kb;
      }
    }
  }

  mg[ws][lane] = kb;
  __syncthreads();
  if (ws == 0) {
    unsigned long long k0 = mg[0][lane];
    unsigned long long k1 = mg[1][lane];
    unsigned long long k2 = mg[2][lane];
    unsigned long long k3 = mg[3][lane];
    k0 = k1 < k0 ? k1 : k0;
    k2 = k3 < k2 ? k3 : k2;
    k0 = k2 < k0 ? k2 : k0;
    if (k0 != ~0ull)
      atomicMin(zkey + (size_t)b * NPIX + pi * IMG_ + pj, k0);
  }
}

// ------------------------------------------------------------------- shading
#define TAP(ty, tx, wexpr)                                                   \
  {                                                                          \
    int ty_ = (ty), tx_ = (tx);                                              \
    float w_ = (wexpr);                                                      \
    float valid_ =                                                           \
        (tx_ >= 0 && tx_ < UV_ && ty_ >= 0 && ty_ < UV_) ? 1.0f : 0.0f;      \
    float wv_ = w_ * valid_;                                                 \
    int cy_ = min(max(ty_, 0), UV_ - 1), cx_ = min(max(tx_, 0), UV_ - 1);    \
    int o_ = cy_ * UV_ + cx_;                                                \
    cr = cr + img[o_] * wv_;                                                 \
    cg = cg + img[UV_ * UV_ + o_] * wv_;                                     \
    cb = cb + img[2 * UV_ * UV_ + o_] * wv_;                                 \
  }

__global__ void __launch_bounds__(256) shade_k(
    const float* __restrict__ vp, const int* __restrict__ faces,
    const float* __restrict__ uv, const float* __restrict__ samp,
    const unsigned long long* __restrict__ zkey, float* __restrict__ out) {
  int idx = blockIdx.x * 256 + threadIdx.x;
  if (idx >= B_ * NPIX) return;
  int b = idx / NPIX;
  int p = idx - b * NPIX;
  int ii = p / IMG_;
  int jj = p - ii * IMG_;

  unsigned long long key = zkey[idx];
  float cr = 0.0f, cg = 0.0f, cb = 0.0f;
  if (key != 0xFFFFFFFFFFFFFFFFull) {
    int f = (int)(key & 0xFFFFFFFFull);
    int ia = faces[f * 3 + 0], ib = faces[f * 3 + 1], ic = faces[f * 3 + 2];
    const float* vb = vp + (size_t)b * NV_ * 3;
    float x0 = vb[ia * 3 + 0], y0 = vb[ia * 3 + 1];
    float x1 = vb[ib * 3 + 0], y1 = vb[ib * 3 + 1];
    float x2 = vb[ic * 3 + 0], y2 = vb[ic * 3 + 1];
    float px = (float)(2 * jj + 1) / 128.0f - 1.0f;
    float py = 1.0f - (float)(2 * ii + 1) / 128.0f;
    float w0 = (x2 - x1) * (py - y1) - (y2 - y1) * (px - x1);
    float w1 = (x0 - x2) * (py - y2) - (y0 - y2) * (px - x2);
    float w2 = (x1 - x0) * (py - y0) - (y1 - y0) * (px - x0);
    float area = (w0 + w1) + w2;
    float s = (area == 0.0f) ? 1.0f : area;
    float b0 = w0 / s, b1 = w1 / s;
    int t0 = min(max((int)floorf(b0 * 3.0f), 0), 2);
    int t1 = min(max((int)floorf(b1 * 3.0f), 0), 2);

    // lazy texture fetch: textures[b,f,t0,t1,*,c] == bilinear(uv_imgs[b],
    // sampler[f, t0*3+t1]); lighting multiplier is exactly 1.0 -> skipped.
    const float* g = samp + ((size_t)f * 9 + (size_t)(t0 * 3 + t1)) * 2;
    float gx = g[0], gy = g[1];
    float x = (gx + 1.0f) * 128.0f - 0.5f;   // (g+1)*(W*0.5)-0.5, W=256
    float y = (gy + 1.0f) * 128.0f - 0.5f;
    float x0f = floorf(x), y0f = floorf(y);
    float wx = x - x0f, wy = y - y0f;
    int xi = (int)x0f, yi = (int)y0f;
    float omwx = 1.0f - wx, omwy = 1.0f - wy;
    const float* img = uv + (size_t)b * 3 * UV_ * UV_;
    // reference accumulation order: (y0,x0)+(y0,x0+1)+(y0+1,x0)+(y0+1,x0+1)
    TAP(yi,     xi,     omwx * omwy)
    TAP(yi,     xi + 1, wx * omwy)
    TAP(yi + 1, xi,     omwx * wy)
    TAP(yi + 1, xi + 1, wx * wy)
  }
  out[((size_t)b * 3 + 0) * NPIX + p] = cr;
  out[((size_t)b * 3 + 1) * NPIX + p] = cg;
  out[((size_t)b * 3 + 2) * NPIX + p] = cb;
}

// ------------------------------------------------------------------- launch
extern "C" void kernel_launch(void* const* d_in, const int* in_sizes, int n_in,
                              void* d_out, int out_size, void* d_ws,
                              size_t ws_size, hipStream_t stream) {
  const float* cam   = (const float*)d_in[0];
  const float* verts = (const float*)d_in[1];
  const float* uv    = (const float*)d_in[2];
  const float* samp  = (const float*)d_in[3];
  const int*   faces = (const int*)d_in[4];

  char* ws = (char*)d_ws;
  size_t o = 0;
  unsigned long long* zkey = (unsigned long long*)(ws + o);
  o += (size_t)B_ * NPIX * 8;                                   // 512 KB
  float* vp = (float*)(ws + o);
  o += ((size_t)B_ * NV_ * 3 * 4 + 1023) & ~1023ull;            // ~331 KB
  int* cnt  = (int*)(ws + o); o += NBIN_ * 4;
  int* offs = (int*)(ws + o); o += NBIN_ * 4;
  int* cur  = (int*)(ws + o); o += NBIN_ * 4;
  int* nC   = (int*)(ws + o); o += 1024;
  int* work = (int*)(ws + o); o += (size_t)MAXC_ * 4;           // 36 KB
  int* list = (int*)(ws + o);                                   // 8 MB

  hipMemsetAsync(zkey, 0xFF, (size_t)B_ * NPIX * 8, stream);
  hipMemsetAsync(cnt, 0, NBIN_ * 4, stream);
  project_k<<<(B_ * NV_ + 255) / 256, 256, 0, stream>>>(cam, verts, vp);
  dim3 bgrid((NF_ + 255) / 256, B_);
  bin_count_k<<<bgrid, 256, 0, stream>>>(vp, faces, cnt);
  scan_k<<<1, NBIN_, 0, stream>>>(cnt, offs, cur, work, nC);
  bin_fill_k<<<bgrid, 256, 0, stream>>>(vp, faces, cur, list);
  raster_k<<<MAXC_, 256, 0, stream>>>(vp, faces, list, cnt, offs, work, nC,
                                      zkey);
  shade_k<<<(B_ * NPIX + 255) / 256, 256, 0, stream>>>(vp, faces, uv, samp,
                                                       zkey, (float*)d_out);
}

// Round 6
// 213.375 us; speedup vs baseline: 14.5864x; 1.1645x over previous
//
#include <hip/hip_runtime.h>
#include <stdint.h>

// Exact fp32 reproduction of the numpy reference requires no FMA contraction
// and identical association order everywhere below.
#pragma clang fp contract(off)

#define B_    4
#define NV_   6890
#define NF_   27552     // 2*13776
#define IMG_  128
#define UV_   256
#define NPIX  (IMG_*IMG_)

#define TS_     8                 // tile edge in pixels
#define TPB_    (IMG_/TS_)        // 16 tiles per row/col
#define NTILE_  (TPB_*TPB_)       // 256 tiles per batch
#define NBIN_   (B_*NTILE_)       // 1024 bins
#define LIST_CAP (2*1024*1024)    // entries (8 MB); measured need ~1.2M
#define MAXC_   (LIST_CAP/256 + NBIN_)  // 9216: hard bound on work chunks

// ---------------------------------------------------------------- projection
__global__ void __launch_bounds__(256) project_k(
    const float* __restrict__ cam, const float* __restrict__ verts,
    float* __restrict__ vp) {
  int idx = blockIdx.x * 256 + threadIdx.x;
  if (idx >= B_ * NV_) return;
  int b = idx / NV_;
  float c0 = cam[b * 3 + 0], c1 = cam[b * 3 + 1], c2 = cam[b * 3 + 2];
  float tz = 500.0f / (64.0f * c0);                  // FLENGTH/(p*cam0), p=64
  const float* src = verts + (size_t)idx * 3;
  float* dst = vp + (size_t)idx * 3;
  dst[0] = c0 * (src[0] + c1);
  dst[1] = c0 * (src[1] + c2);
  dst[2] = src[2] + tz;
}

// ------------------------------------------------------------------- binning
// Backface cull (area_c < -1e-3, bit-safe bound proven in R1) + bbox(+-1px)
// -> range of overlapped 8x8 tiles. +-1 px margin: accepted pixels can exceed
// the fp bbox by <~1e-3 px only (fp error of w-tests ~1e-5 NDC).
__device__ __forceinline__ int face_tiles(
    const float* __restrict__ vp, const int* __restrict__ faces, int b, int f,
    int& tx0, int& tx1, int& ty0, int& ty1) {
  int ia = faces[f * 3 + 0], ib = faces[f * 3 + 1], ic = faces[f * 3 + 2];
  const float* vb = vp + (size_t)b * NV_ * 3;
  float x0 = vb[ia * 3 + 0], y0 = vb[ia * 3 + 1];
  float x1 = vb[ib * 3 + 0], y1 = vb[ib * 3 + 1];
  float x2 = vb[ic * 3 + 0], y2 = vb[ic * 3 + 1];
  float area_c = (x1 - x0) * (y2 - y0) - (y1 - y0) * (x2 - x0);
  if (area_c < -1e-3f) return 0;
  float xmn = fminf(x0, fminf(x1, x2)), xmx = fmaxf(x0, fmaxf(x1, x2));
  float ymn = fminf(y0, fminf(y1, y2)), ymx = fmaxf(y0, fmaxf(y1, y2));
  int jlo = (int)floorf((xmn + 1.0f) * 64.0f - 0.5f) - 1;
  int jhi = (int)ceilf ((xmx + 1.0f) * 64.0f - 0.5f) + 1;
  int ilo = (int)floorf((1.0f - ymx) * 64.0f - 0.5f) - 1;
  int ihi = (int)ceilf ((1.0f - ymn) * 64.0f - 0.5f) + 1;
  if (jhi < 0 || ihi < 0 || jlo > IMG_ - 1 || ilo > IMG_ - 1) return 0;
  jlo = max(jlo, 0); ilo = max(ilo, 0);
  jhi = min(jhi, IMG_ - 1); ihi = min(ihi, IMG_ - 1);
  tx0 = jlo >> 3; tx1 = jhi >> 3; ty0 = ilo >> 3; ty1 = ihi >> 3;
  return 1;
}

// Block-local LDS count aggregation (R5-validated). Also caches the packed
// tile rect per (b,f) so bin_fill_k skips recomputing face_tiles.
__global__ void __launch_bounds__(256) bin_count_k(
    const float* __restrict__ vp, const int* __restrict__ faces,
    int* __restrict__ cnt, int* __restrict__ rects) {
  __shared__ int scnt[NTILE_];
  int f = blockIdx.x * 256 + threadIdx.x;
  int b = blockIdx.y;
  scnt[threadIdx.x] = 0;
  __syncthreads();
  int tx0, tx1, ty0, ty1;
  int valid = (f < NF_) ? face_tiles(vp, faces, b, f, tx0, tx1, ty0, ty1) : 0;
  if (f < NF_)
    rects[(size_t)b * NF_ + f] =
        valid ? (tx0 | (tx1 << 4) | (ty0 << 8) | (ty1 << 12) | (1 << 16)) : 0;
  if (valid)
    for (int ty = ty0; ty <= ty1; ++ty)
      for (int tx = tx0; tx <= tx1; ++tx)
        atomicAdd(&scnt[ty * TPB_ + tx], 1);
  __syncthreads();
  int t = threadIdx.x;
  int v = scnt[t];
  if (v > 0) atomicAdd(&cnt[b * NTILE_ + t], v);
}

// Scan bin counts -> offsets; also scan chunk counts (ceil(cnt/256)) into a
// flat balanced work list of (bin, chunk) pairs; total chunk count -> nC.
__global__ void __launch_bounds__(1024) scan_k(
    const int* __restrict__ cnt, int* __restrict__ off, int* __restrict__ cur,
    int* __restrict__ work, int* __restrict__ nC) {
  __shared__ int sm[NBIN_];
  int t = threadIdx.x;
  int v = cnt[t];
  sm[t] = v;
  __syncthreads();
  for (int d = 1; d < NBIN_; d <<= 1) {
    int u = (t >= d) ? sm[t - d] : 0;
    __syncthreads();
    sm[t] += u;
    __syncthreads();
  }
  int o = sm[t] - v;
  off[t] = o;
  cur[t] = o;
  int nch = (v + 255) >> 8;
  __syncthreads();
  sm[t] = nch;
  __syncthreads();
  for (int d = 1; d < NBIN_; d <<= 1) {
    int u = (t >= d) ? sm[t - d] : 0;
    __syncthreads();
    sm[t] += u;
    __syncthreads();
  }
  int cb = sm[t] - nch;
  if (t == NBIN_ - 1) nC[0] = sm[t];
  for (int c = 0; c < nch; ++c) work[cb + c] = t | (c << 10);
}

// Block-local fill (R5-validated), using the cached rects from bin_count_k.
__global__ void __launch_bounds__(256) bin_fill_k(
    const int* __restrict__ rects, int* __restrict__ cur,
    int* __restrict__ list) {
  __shared__ int scnt[NTILE_];
  __shared__ int sbase[NTILE_];
  int f = blockIdx.x * 256 + threadIdx.x;
  int b = blockIdx.y;
  scnt[threadIdx.x] = 0;
  __syncthreads();
  int rv = (f < NF_) ? rects[(size_t)b * NF_ + f] : 0;
  int valid = rv >> 16;
  int tx0 = rv & 15, tx1 = (rv >> 4) & 15;
  int ty0 = (rv >> 8) & 15, ty1 = (rv >> 12) & 15;
  if (valid)
    for (int ty = ty0; ty <= ty1; ++ty)
      for (int tx = tx0; tx <= tx1; ++tx)
        atomicAdd(&scnt[ty * TPB_ + tx], 1);
  __syncthreads();
  int t = threadIdx.x;
  int v = scnt[t];
  if (v > 0) sbase[t] = atomicAdd(&cur[b * NTILE_ + t], v);
  __syncthreads();
  scnt[t] = 0;            // reuse as per-bin rank counter
  __syncthreads();
  if (valid)
    for (int ty = ty0; ty <= ty1; ++ty)
      for (int tx = tx0; tx <= tx1; ++tx) {
        int bin = ty * TPB_ + tx;
        int r = atomicAdd(&scnt[bin], 1);
        int slot = sbase[bin] + r;
        if (slot < LIST_CAP) list[slot] = f;
      }
}

// ---------------------------------------------------------------- rasterizer
// One 256-thread block per work chunk (bin, 256 faces). Inside test
// `area>0 && !(min3(w)<0)` == reference's post-divide b>=0 (R3-R5 validated,
// absmax 0.0; min3 preserves -0 semantics since !(-0<0)==true).
//
// R6: approximate-depth gate. zpa = (area*z0z1z2)*rcp(w0*z1z2+w1*z0z2+w2*z0z1)
// has relative error <= ~2e-5 (positive sums, z>0, v_rcp ~1ulp). The exact
// reference divide chain (7 IEEE divides) runs ONLY if !(zpa > kb_z*1.001):
// skip implies zp > kb_z strictly, so the winning key is bit-identical.
// gate starts as NaN (kb empty) -> first accept always exact. Per pixel only
// ~ln(270)=6 prefix-minima run the exact chain instead of ~270.
__global__ void __launch_bounds__(256) raster_k(
    const float* __restrict__ vp, const int* __restrict__ faces,
    const int* __restrict__ list, const int* __restrict__ cnt,
    const int* __restrict__ off, const int* __restrict__ work,
    const int* __restrict__ nC, unsigned long long* __restrict__ zkey) {
  __shared__ float4 fd[4][5][64];   // [wave][field][lane]: 8-way write banks
  __shared__ unsigned long long mg[4][64];
  int bid = blockIdx.x;
  if (bid >= nC[0]) return;                       // block-uniform exit
  int wkv = work[bid];
  int bin = wkv & (NBIN_ - 1);
  int chunk = wkv >> 10;
  int b = bin >> 8;
  int t = bin & 255;
  int tyT = t >> 4, txT = t & 15;
  int ws = threadIdx.x >> 6, lane = threadIdx.x & 63;
  int pi = tyT * TS_ + (lane >> 3);
  int pj = txT * TS_ + (lane & 7);
  // exact: (2j+1)/128-1 and 1-(2i+1)/128 are multiples of 2^-7 in [-1,1]
  float px = fmaf((float)pj, 0.015625f, -0.9921875f);
  float py = fmaf((float)pi, -0.015625f, 0.9921875f);

  int n = cnt[bin];
  int seg = (chunk << 8) + (ws << 6);
  int base0 = off[bin] + seg;
  int mw = min(n - seg, 64);
  mw = max(mw, 0);

  if (lane < mw) {
    int fid = list[base0 + lane];
    int ia = faces[fid * 3 + 0], ib = faces[fid * 3 + 1],
        ic = faces[fid * 3 + 2];
    const float* vb = vp + (size_t)b * NV_ * 3;
    float X0 = vb[ia * 3 + 0], Y0 = vb[ia * 3 + 1], Z0 = vb[ia * 3 + 2];
    float X1 = vb[ib * 3 + 0], Y1 = vb[ib * 3 + 1], Z1 = vb[ib * 3 + 2];
    float X2 = vb[ic * 3 + 0], Y2 = vb[ic * 3 + 1], Z2 = vb[ic * 3 + 2];
    fd[ws][0][lane] = make_float4(X2 - X1, Y2 - Y1, X1, Y1);   // d21, v1
    fd[ws][1][lane] = make_float4(X0 - X2, Y0 - Y2, X2, Y2);   // d02, v2
    fd[ws][2][lane] = make_float4(X1 - X0, Y1 - Y0, X0, Y0);   // d10, v0
    fd[ws][3][lane] = make_float4(Z0, Z1, Z2, __int_as_float(fid));
    fd[ws][4][lane] =
        make_float4(Z1 * Z2, Z0 * Z2, Z0 * Z1, Z0 * Z1 * Z2);  // approx prods
  }
  __syncthreads();

  unsigned long long kb = ~0ull;
  float gate = __uint_as_float(0xFFFFFFFFu);       // NaN -> first accept exact
  for (int q = 0; q < mw; ++q) {
    float4 A = fd[ws][0][q];
    float4 Bv = fd[ws][1][q];
    float4 Cv = fd[ws][2][q];
    float w0 = A.x * (py - A.w) - A.y * (px - A.z);
    float w1 = Bv.x * (py - Bv.w) - Bv.y * (px - Bv.z);
    float w2 = Cv.x * (py - Cv.w) - Cv.y * (px - Cv.z);
    float area = (w0 + w1) + w2;
    float mn = fminf(w0, fminf(w1, w2));
    if (area > 0.0f && !(mn < 0.0f)) {
      float4 P = fd[ws][4][q];
      float num = (w0 * P.x + w1 * P.y) + w2 * P.z;   // approx: any order
      float zpa = (area * P.w) * __builtin_amdgcn_rcpf(num);
      if (!(zpa > gate)) {                            // NaN-safe gate
        float4 Z = fd[ws][3][q];
        float b0 = w0 / area, b1 = w1 / area, b2 = w2 / area;
        float invz = (b0 / Z.x + b1 / Z.y) + b2 / Z.z;
        float zp = 1.0f / (invz == 0.0f ? 1.0f : invz);
        if (zp > 0.1f && zp < 25.0f) {
          unsigned long long key =
              ((unsigned long long)__float_as_uint(zp) << 32) |
              (unsigned int)__float_as_int(Z.w);
          if (key < kb) {
            kb = key;
            gate = __uint_as_float((unsigned int)(kb >> 32)) * 1.001f;
          }
        }
      }
    }
  }

  mg[ws][lane] = kb;
  __syncthreads();
  if (ws == 0) {
    unsigned long long k0 = mg[0][lane];
    unsigned long long k1 = mg[1][lane];
    unsigned long long k2 = mg[2][lane];
    unsigned long long k3 = mg[3][lane];
    k0 = k1 < k0 ? k1 : k0;
    k2 = k3 < k2 ? k3 : k2;
    k0 = k2 < k0 ? k2 : k0;
    if (k0 != ~0ull)
      atomicMin(zkey + (size_t)b * NPIX + pi * IMG_ + pj, k0);
  }
}

// ------------------------------------------------------------------- shading
#define TAP(ty, tx, wexpr)                                                   \
  {                                                                          \
    int ty_ = (ty), tx_ = (tx);                                              \
    float w_ = (wexpr);                                                      \
    float valid_ =                                                           \
        (tx_ >= 0 && tx_ < UV_ && ty_ >= 0 && ty_ < UV_) ? 1.0f : 0.0f;      \
    float wv_ = w_ * valid_;                                                 \
    int cy_ = min(max(ty_, 0), UV_ - 1), cx_ = min(max(tx_, 0), UV_ - 1);    \
    int o_ = cy_ * UV_ + cx_;                                                \
    cr = cr + img[o_] * wv_;                                                 \
    cg = cg + img[UV_ * UV_ + o_] * wv_;                                     \
    cb = cb + img[2 * UV_ * UV_ + o_] * wv_;                                 \
  }

__global__ void __launch_bounds__(256) shade_k(
    const float* __restrict__ vp, const int* __restrict__ faces,
    const float* __restrict__ uv, const float* __restrict__ samp,
    const unsigned long long* __restrict__ zkey, float* __restrict__ out) {
  int idx = blockIdx.x * 256 + threadIdx.x;
  if (idx >= B_ * NPIX) return;
  int b = idx / NPIX;
  int p = idx - b * NPIX;
  int ii = p / IMG_;
  int jj = p - ii * IMG_;

  unsigned long long key = zkey[idx];
  float cr = 0.0f, cg = 0.0f, cb = 0.0f;
  if (key != 0xFFFFFFFFFFFFFFFFull) {
    int f = (int)(key & 0xFFFFFFFFull);
    int ia = faces[f * 3 + 0], ib = faces[f * 3 + 1], ic = faces[f * 3 + 2];
    const float* vb = vp + (size_t)b * NV_ * 3;
    float x0 = vb[ia * 3 + 0], y0 = vb[ia * 3 + 1];
    float x1 = vb[ib * 3 + 0], y1 = vb[ib * 3 + 1];
    float x2 = vb[ic * 3 + 0], y2 = vb[ic * 3 + 1];
    float px = (float)(2 * jj + 1) / 128.0f - 1.0f;
    float py = 1.0f - (float)(2 * ii + 1) / 128.0f;
    float w0 = (x2 - x1) * (py - y1) - (y2 - y1) * (px - x1);
    float w1 = (x0 - x2) * (py - y2) - (y0 - y2) * (px - x2);
    float w2 = (x1 - x0) * (py - y0) - (y1 - y0) * (px - x0);
    float area = (w0 + w1) + w2;
    float s = (area == 0.0f) ? 1.0f : area;
    float b0 = w0 / s, b1 = w1 / s;
    int t0 = min(max((int)floorf(b0 * 3.0f), 0), 2);
    int t1 = min(max((int)floorf(b1 * 3.0f), 0), 2);

    // lazy texture fetch: textures[b,f,t0,t1,*,c] == bilinear(uv_imgs[b],
    // sampler[f, t0*3+t1]); lighting multiplier is exactly 1.0 -> skipped.
    const float* g = samp + ((size_t)f * 9 + (size_t)(t0 * 3 + t1)) * 2;
    float gx = g[0], gy = g[1];
    float x = (gx + 1.0f) * 128.0f - 0.5f;   // (g+1)*(W*0.5)-0.5, W=256
    float y = (gy + 1.0f) * 128.0f - 0.5f;
    float x0f = floorf(x), y0f = floorf(y);
    float wx = x - x0f, wy = y - y0f;
    int xi = (int)x0f, yi = (int)y0f;
    float omwx = 1.0f - wx, omwy = 1.0f - wy;
    const float* img = uv + (size_t)b * 3 * UV_ * UV_;
    // reference accumulation order: (y0,x0)+(y0,x0+1)+(y0+1,x0)+(y0+1,x0+1)
    TAP(yi,     xi,     omwx * omwy)
    TAP(yi,     xi + 1, wx * omwy)
    TAP(yi + 1, xi,     omwx * wy)
    TAP(yi + 1, xi + 1, wx * wy)
  }
  out[((size_t)b * 3 + 0) * NPIX + p] = cr;
  out[((size_t)b * 3 + 1) * NPIX + p] = cg;
  out[((size_t)b * 3 + 2) * NPIX + p] = cb;
}

// ------------------------------------------------------------------- launch
extern "C" void kernel_launch(void* const* d_in, const int* in_sizes, int n_in,
                              void* d_out, int out_size, void* d_ws,
                              size_t ws_size, hipStream_t stream) {
  const float* cam   = (const float*)d_in[0];
  const float* verts = (const float*)d_in[1];
  const float* uv    = (const float*)d_in[2];
  const float* samp  = (const float*)d_in[3];
  const int*   faces = (const int*)d_in[4];

  char* ws = (char*)d_ws;
  size_t o = 0;
  unsigned long long* zkey = (unsigned long long*)(ws + o);
  o += (size_t)B_ * NPIX * 8;                                   // 512 KB
  float* vp = (float*)(ws + o);
  o += ((size_t)B_ * NV_ * 3 * 4 + 1023) & ~1023ull;            // ~331 KB
  int* cnt   = (int*)(ws + o); o += NBIN_ * 4;
  int* offs  = (int*)(ws + o); o += NBIN_ * 4;
  int* cur   = (int*)(ws + o); o += NBIN_ * 4;
  int* nC    = (int*)(ws + o); o += 1024;
  int* work  = (int*)(ws + o); o += (size_t)MAXC_ * 4;          // 36 KB
  int* rects = (int*)(ws + o); o += (size_t)B_ * NF_ * 4;       // 440 KB
  int* list  = (int*)(ws + o);                                  // 8 MB

  hipMemsetAsync(zkey, 0xFF, (size_t)B_ * NPIX * 8, stream);
  hipMemsetAsync(cnt, 0, NBIN_ * 4, stream);
  project_k<<<(B_ * NV_ + 255) / 256, 256, 0, stream>>>(cam, verts, vp);
  dim3 bgrid((NF_ + 255) / 256, B_);
  bin_count_k<<<bgrid, 256, 0, stream>>>(vp, faces, cnt, rects);
  scan_k<<<1, NBIN_, 0, stream>>>(cnt, offs, cur, work, nC);
  bin_fill_k<<<bgrid, 256, 0, stream>>>(rects, cur, list);
  raster_k<<<MAXC_, 256, 0, stream>>>(vp, faces, list, cnt, offs, work, nC,
                                      zkey);
  shade_k<<<(B_ * NPIX + 255) / 256, 256, 0, stream>>>(vp, faces, uv, samp,
                                                       zkey, (float*)d_out);
}